// Round 9
// baseline (416.279 us; speedup 1.0000x reference)
//
#include <hip/hip_runtime.h>
#include <hip/hip_bf16.h>
#include <math.h>

typedef short short8 __attribute__((ext_vector_type(8)));
typedef short short4v __attribute__((ext_vector_type(4)));
typedef float f32x4 __attribute__((ext_vector_type(4)));
typedef __bf16 bf16x8 __attribute__((ext_vector_type(8)));

#define DEVI __device__ __forceinline__

DEVI float bf2f(short u) {
  union { unsigned int u32; float f; } c;
  c.u32 = ((unsigned int)(unsigned short)u) << 16;
  return c.f;
}
DEVI short f2bf(float f) {
  __hip_bfloat16 h = __float2bfloat16(f);
  unsigned short u;
  __builtin_memcpy(&u, &h, 2);
  return (short)u;
}
DEVI f32x4 mfma16(bf16x8 a, bf16x8 b, f32x4 c) {
  return __builtin_amdgcn_mfma_f32_16x16x32_bf16(a, b, c, 0, 0, 0);
}

#define GLL16(gsrc, ldst) __builtin_amdgcn_global_load_lds( \
    (__attribute__((address_space(1))) void*)(gsrc), \
    (__attribute__((address_space(3))) void*)(ldst), 16, 0, 0)

// ---------------- prep: x -> bf16 (B,C,L) and transposed (B,L,C) ----------------
__global__ __launch_bounds__(256) void k_prep_x(const float* __restrict__ x,
                                                short* __restrict__ xbf,
                                                short* __restrict__ xT) {
  __shared__ short T[64][66];
  int t = threadIdx.x;
  int lt = blockIdx.x & 127;
  int ct = (blockIdx.x >> 7) & 1;
  int b  = blockIdx.x >> 8;
  int c0 = ct << 6, l0 = lt << 6;
  int i = t >> 2, j4 = (t & 3) << 4;
  const float* src = x + (size_t)(b * 128 + c0 + i) * 8192 + l0 + j4;
  short hv[16];
#pragma unroll
  for (int e = 0; e < 16; e += 4) {
    float4 v = *(const float4*)(src + e);
    hv[e] = f2bf(v.x); hv[e + 1] = f2bf(v.y); hv[e + 2] = f2bf(v.z); hv[e + 3] = f2bf(v.w);
  }
  short8 o0, o1;
#pragma unroll
  for (int e = 0; e < 8; ++e) { o0[e] = hv[e]; o1[e] = hv[8 + e]; }
  short* dst = xbf + (size_t)(b * 128 + c0 + i) * 8192 + l0 + j4;
  *(short8*)dst = o0;
  *(short8*)(dst + 8) = o1;
#pragma unroll
  for (int e = 0; e < 16; ++e) T[i][j4 + e] = hv[e];
  __syncthreads();
  int jj = t >> 2, i4 = (t & 3) << 4;
  short8 p0, p1;
#pragma unroll
  for (int e = 0; e < 8; ++e) { p0[e] = T[i4 + e][jj]; p1[e] = T[i4 + 8 + e][jj]; }
  short* d2 = xT + ((size_t)b * 8192 + l0 + jj) * 128 + c0 + i4;
  *(short8*)d2 = p0;
  *(short8*)(d2 + 8) = p1;
}

// ---------------- prep: forward twiddle table Tf [1024][8192], rows 2m=cos, 2m+1=-sin ----
__global__ __launch_bounds__(256) void k_prep_tf(short* __restrict__ tf) {
  int n = blockIdx.x >> 2;
  int l0 = ((blockIdx.x & 3) << 11) + (threadIdx.x << 3);
  int m = n >> 1;
  int odd = n & 1;
  short8 o;
#pragma unroll
  for (int e = 0; e < 8; ++e) {
    int l = l0 + e;
    int r = (m * l) & 8191;
    float s, c;
    sincospif((float)r * (1.0f / 4096.0f), &s, &c);
    o[e] = f2bf(odd ? -s : c);
  }
  *(short8*)(tf + (size_t)n * 8192 + l0) = o;
}

// ---------------- prep: inverse twiddle Ti [8192][1024], cols k<512 cos, >=512 sin ------
__global__ __launch_bounds__(256) void k_prep_ti(short* __restrict__ ti) {
  int l = blockIdx.x;
  int k0 = threadIdx.x << 2;
  short4v o;
#pragma unroll
  for (int e = 0; e < 4; ++e) {
    int k = k0 + e;
    int m = (k < 512) ? k : (k - 512);
    int r = (m * l) & 8191;
    float s, c;
    sincospif((float)r * (1.0f / 4096.0f), &s, &c);
    o[e] = f2bf((k < 512) ? c : s);
  }
  *(short4v*)(ti + (size_t)l * 1024 + k0) = o;
}

// ---------------- prep: pack weights bf16, FRAGMENT-MAJOR for coalesced wave loads ----
__global__ __launch_bounds__(256) void k_prep_w(const float* __restrict__ w1,
                                                const float* __restrict__ w2,
                                                const float* __restrict__ w3,
                                                const float* __restrict__ pw_w,
                                                short* __restrict__ w12f,
                                                short* __restrict__ w3f,
                                                short* __restrict__ pwb) {
  int idx = blockIdx.x * 256 + threadIdx.x;
  if (idx < 98304) {
    int e = idx & 7, lane = (idx >> 3) & 63, ks = (idx >> 9) & 3, nt = idx >> 11;
    int rowk = lane & 15, kg = lane >> 4;
    int n = nt * 16 + rowk;          // 0..767
    int k = ks * 32 + kg * 8 + e;    // 0..127
    float v = 0.f;
    if (n < 352) v = w1[n * 128 + k];
    else if (n >= 384 && n < 736) v = w2[(n - 384) * 128 + k];
    w12f[idx] = f2bf(v);
  } else if (idx < 147456) {
    int q = idx - 98304;             // 0..49151
    int e = q & 7, lane = (q >> 3) & 63;
    int rest = q >> 9;               // 0..95
    int nt = rest / 12, ks = rest - nt * 12;
    int rowk = lane & 15, kg = lane >> 4;
    int n = nt * 16 + rowk;          // 0..127
    int k = ks * 32 + kg * 8 + e;    // 0..383
    w3f[q] = f2bf(k < 352 ? w3[n * 352 + k] : 0.f);
  } else if (idx < 163840) {
    int q = idx - 147456;
    pwb[q] = f2bf(pw_w[q]);
  }
}

// ---------------- prep: bias[b][o] = tb+pw_b+dw_b + silu(t_emb) @ tw^T ----------------
__global__ __launch_bounds__(256) void k_prep_bias(const float* __restrict__ t_emb,
                                                   const float* __restrict__ tw,
                                                   const float* __restrict__ tb,
                                                   const float* __restrict__ pw_b,
                                                   const float* __restrict__ dw_b,
                                                   float* __restrict__ bias) {
  __shared__ float s[256];
  int b = blockIdx.x, t = threadIdx.x;
  float v = t_emb[b * 256 + t];
  s[t] = v / (1.0f + __expf(-v));
  __syncthreads();
  if (t < 128) {
    float acc = tb[t] + pw_b[t] + dw_b[t];
    for (int j = 0; j < 256; ++j) acc += s[j] * tw[t * 256 + j];
    bias[b * 128 + t] = acc;
  }
}

__global__ __launch_bounds__(256) void k_zero(float4* __restrict__ p, int n4) {
  int i = blockIdx.x * 256 + threadIdx.x;
  if (i < n4) p[i] = make_float4(0.f, 0.f, 0.f, 0.f);
}

// ---------------- forward partial DFT GEMM: X[1024][1024] += x_bf @ Tf^T, split-K=8 ----
// 3-buffer, depth-2 prefetch, counted vmcnt (never 0 in steady state).
__global__ __launch_bounds__(256, 3) void k_fwd(const short* __restrict__ A,
                                                const short* __restrict__ Bt,
                                                float* __restrict__ X) {
  __shared__ short As[12288];   // 3 x [128][32]
  __shared__ short Bs[12288];
  int t = threadIdx.x;
  int nt = blockIdx.x & 7;
  int mt = (blockIdx.x >> 3) & 7;
  int kc = blockIdx.x >> 6;
  int lane = t & 63, wv = t >> 6;
  int wr = wv >> 1, wc = wv & 1;

  int rA = t >> 2, g = t & 3;
  int gs0 = (g ^ ((rA >> 1) & 3)) << 3;
  int rB = rA + 64;
  int gs1 = (g ^ ((rB >> 1) & 3)) << 3;

  const short* aS0 = A + (size_t)(mt * 128 + rA) * 8192 + kc * 1024 + gs0;
  const short* aS1 = A + (size_t)(mt * 128 + rB) * 8192 + kc * 1024 + gs1;
  const short* bS0 = Bt + (size_t)(nt * 128 + rA) * 8192 + kc * 1024 + gs0;
  const short* bS1 = Bt + (size_t)(nt * 128 + rB) * 8192 + kc * 1024 + gs1;

  f32x4 acc[4][4];
#pragma unroll
  for (int i = 0; i < 4; ++i)
#pragma unroll
    for (int j = 0; j < 4; ++j) acc[i][j] = (f32x4){0.f, 0.f, 0.f, 0.f};

  auto stage = [&](int p, int ks) {
    int ao = p * 4096;
    int ko = ks * 32;
    GLL16(aS0 + ko, &As[ao + t * 8]);
    GLL16(aS1 + ko, &As[ao + 2048 + t * 8]);
    GLL16(bS0 + ko, &Bs[ao + t * 8]);
    GLL16(bS1 + ko, &Bs[ao + 2048 + t * 8]);
  };

  stage(0, 0);
  stage(1, 1);

  int rowk = lane & 15, kg = lane >> 4;

  for (int ks = 0; ks < 32; ++ks) {
    int p = ks % 3;
    __builtin_amdgcn_s_barrier();            // protect buffer (ks+2)%3 from iter ks-1 readers
    if (ks + 2 < 32) stage((ks + 2) % 3, ks + 2);
    if (ks < 30)      { asm volatile("s_waitcnt vmcnt(8)" ::: "memory"); }
    else if (ks == 30){ asm volatile("s_waitcnt vmcnt(4)" ::: "memory"); }
    else              { asm volatile("s_waitcnt vmcnt(0)" ::: "memory"); }
    __builtin_amdgcn_s_barrier();            // all waves' ks-loads landed
    __builtin_amdgcn_sched_barrier(0);
    bf16x8 af[4], bfr[4];
#pragma unroll
    for (int fr = 0; fr < 4; ++fr) {
      int rr = wr * 64 + fr * 16 + rowk;
      int gg = kg ^ ((rr >> 1) & 3);
      af[fr] = *(const bf16x8*)(&As[p * 4096 + rr * 32 + gg * 8]);
    }
#pragma unroll
    for (int fc = 0; fc < 4; ++fc) {
      int rr = wc * 64 + fc * 16 + rowk;
      int gg = kg ^ ((rr >> 1) & 3);
      bfr[fc] = *(const bf16x8*)(&Bs[p * 4096 + rr * 32 + gg * 8]);
    }
#pragma unroll
    for (int fr = 0; fr < 4; ++fr)
#pragma unroll
      for (int fc = 0; fc < 4; ++fc)
        acc[fr][fc] = mfma16(af[fr], bfr[fc], acc[fr][fc]);
  }

  int rbase = mt * 128 + wr * 64 + (lane >> 4) * 4;
  int cbase = nt * 128 + wc * 64 + (lane & 15);
#pragma unroll
  for (int fr = 0; fr < 4; ++fr)
#pragma unroll
    for (int fc = 0; fc < 4; ++fc)
#pragma unroll
      for (int j = 0; j < 4; ++j)
        unsafeAtomicAdd(&X[(size_t)(rbase + fr * 16 + j) * 1024 + cbase + fc * 16],
                        acc[fr][fc][j]);
}

// ---------------- spectral mix: D[(b,o)][k] = scaled(rot*(W^T X) - X) ----------------
__global__ __launch_bounds__(512) void k_spec(const float* __restrict__ X,
                                              const float* __restrict__ wre,
                                              const float* __restrict__ wim,
                                              const float* __restrict__ shifts,
                                              short* __restrict__ D) {
  __shared__ float red[16][256];
  int t = threadIdx.x;
  int tt = t & 255;
  int ch = t >> 8;
  int mt = blockIdx.x & 31, ot = blockIdx.x >> 5;
  int m = mt * 16 + (tt & 15);
  int o = ot * 16 + (tt >> 4);
  float ar[8], ai[8];
#pragma unroll
  for (int b = 0; b < 8; ++b) { ar[b] = 0.f; ai[b] = 0.f; }
  int cb = ch * 64;
  const float* wrp = wre + (size_t)(cb * 128 + o) * 512 + m;
  const float* wip = wim + (size_t)(cb * 128 + o) * 512 + m;
  const float* Xp = X + 2 * m;
#pragma unroll 4
  for (int cc = 0; cc < 64; ++cc) {
    float wr = wrp[(size_t)cc * 65536];
    float wi = wip[(size_t)cc * 65536];
    int c = cb + cc;
#pragma unroll
    for (int b = 0; b < 8; ++b) {
      float2 xv = *(const float2*)(Xp + (size_t)(b * 128 + c) * 1024);
      ar[b] += xv.x * wr - xv.y * wi;
      ai[b] += xv.x * wi + xv.y * wr;
    }
  }
  if (ch) {
#pragma unroll
    for (int b = 0; b < 8; ++b) { red[b * 2][tt] = ar[b]; red[b * 2 + 1][tt] = ai[b]; }
  }
  __syncthreads();
  if (!ch) {
#pragma unroll
    for (int b = 0; b < 8; ++b) { ar[b] += red[b * 2][tt]; ai[b] += red[b * 2 + 1][tt]; }
    float phi = -6.283185307179586f * shifts[o] * (float)m;
    float sp, cp;
    sincosf(phi, &sp, &cp);
    float sc = (m == 0 ? 1.0f : 2.0f) * (1.0f / 8192.0f);
#pragma unroll
    for (int b = 0; b < 8; ++b) {
      float yr = ar[b] * cp - ai[b] * sp;
      float yi = ar[b] * sp + ai[b] * cp;
      float2 xo = *(const float2*)(X + (size_t)(b * 128 + o) * 1024 + 2 * m);
      D[((size_t)b * 128 + o) * 1024 + m]       = f2bf(sc * (yr - xo.x));
      D[((size_t)b * 128 + o) * 1024 + 512 + m] = f2bf(-sc * (yi - xo.y));
    }
  }
}

// -------- inverse DFT + pointwise + depthwise + bias + x + RMSNorm*norm_w -> hn (B,L,C) ----
// 3-buffer depth-2 pipeline; coalesced hn store via LDS bounce.
__global__ __launch_bounds__(256, 3) void k_inv(const short* __restrict__ Ti,
                                                const short* __restrict__ D,
                                                const short* __restrict__ xT,
                                                const short* __restrict__ pwb,
                                                const float* __restrict__ dww,
                                                const float* __restrict__ bias,
                                                const float* __restrict__ nw,
                                                short* __restrict__ hn) {
  __shared__ short Sm[24576];   // 48KB: A bufs [3][4096] @0 ; B bufs [3][4096] @12288
                                // epilogue reuse: x tile / hn bounce [128][128] @0
  __shared__ short xedge[256];
  __shared__ float rsS[2][128];
  int t = threadIdx.x;
  int lt = blockIdx.x & 63;
  int b  = blockIdx.x >> 6;
  int l0 = lt << 7;
  int lane = t & 63, wv = t >> 6;
  int wr = wv >> 1, wc = wv & 1;

  int rA = t >> 2, g = t & 3;
  int gs0 = (g ^ ((rA >> 1) & 3)) << 3;
  int rB = rA + 64;
  int gs1 = (g ^ ((rB >> 1) & 3)) << 3;

  const short* a1_0 = Ti + (size_t)(l0 + rA) * 1024 + gs0;
  const short* a1_1 = Ti + (size_t)(l0 + rB) * 1024 + gs1;
  const short* b1_0 = D + (size_t)(b * 128 + rA) * 1024 + gs0;
  const short* b1_1 = D + (size_t)(b * 128 + rB) * 1024 + gs1;
  const short* a2_0 = xT + ((size_t)b * 8192 + l0 + rA) * 128 + gs0;
  const short* a2_1 = xT + ((size_t)b * 8192 + l0 + rB) * 128 + gs1;
  const short* b2_0 = pwb + rA * 128 + gs0;
  const short* b2_1 = pwb + rB * 128 + gs1;

  f32x4 acc[4][4];
#pragma unroll
  for (int i = 0; i < 4; ++i)
#pragma unroll
    for (int j = 0; j < 4; ++j) acc[i][j] = (f32x4){0.f, 0.f, 0.f, 0.f};

  auto stage = [&](int p, int ks) {
    int ao = p * 4096;
    int bo = 12288 + p * 4096;
    if (ks < 32) {
      int ko = ks * 32;
      GLL16(a1_0 + ko, &Sm[ao + t * 8]);
      GLL16(a1_1 + ko, &Sm[ao + 2048 + t * 8]);
      GLL16(b1_0 + ko, &Sm[bo + t * 8]);
      GLL16(b1_1 + ko, &Sm[bo + 2048 + t * 8]);
    } else {
      int ko = (ks - 32) * 32;
      GLL16(a2_0 + ko, &Sm[ao + t * 8]);
      GLL16(a2_1 + ko, &Sm[ao + 2048 + t * 8]);
      GLL16(b2_0 + ko, &Sm[bo + t * 8]);
      GLL16(b2_1 + ko, &Sm[bo + 2048 + t * 8]);
    }
  };

  stage(0, 0);
  stage(1, 1);

  int rowk = lane & 15, kg = lane >> 4;
  for (int ks = 0; ks < 36; ++ks) {
    int p = ks % 3;
    __builtin_amdgcn_s_barrier();
    if (ks + 2 < 36) stage((ks + 2) % 3, ks + 2);
    if (ks < 34)      { asm volatile("s_waitcnt vmcnt(8)" ::: "memory"); }
    else if (ks == 34){ asm volatile("s_waitcnt vmcnt(4)" ::: "memory"); }
    else              { asm volatile("s_waitcnt vmcnt(0)" ::: "memory"); }
    __builtin_amdgcn_s_barrier();
    __builtin_amdgcn_sched_barrier(0);
    bf16x8 af[4], bfr[4];
#pragma unroll
    for (int fr = 0; fr < 4; ++fr) {
      int rr = wr * 64 + fr * 16 + rowk;
      int gg = kg ^ ((rr >> 1) & 3);
      af[fr] = *(const bf16x8*)(&Sm[p * 4096 + rr * 32 + gg * 8]);
    }
#pragma unroll
    for (int fc = 0; fc < 4; ++fc) {
      int rr = wc * 64 + fc * 16 + rowk;
      int gg = kg ^ ((rr >> 1) & 3);
      bfr[fc] = *(const bf16x8*)(&Sm[12288 + p * 4096 + rr * 32 + gg * 8]);
    }
#pragma unroll
    for (int fr = 0; fr < 4; ++fr)
#pragma unroll
      for (int fc = 0; fc < 4; ++fc)
        acc[fr][fc] = mfma16(af[fr], bfr[fc], acc[fr][fc]);
  }

  // restage x tile (rows l0..l0+127) + edge rows into LDS
  __syncthreads();
  for (int i = t; i < 2080; i += 256) {
    if (i < 2048) {
      int row = i >> 4, seg = i & 15;
      short8 v = *(const short8*)(xT + ((size_t)b * 8192 + l0 + row) * 128 + seg * 8);
      *(short8*)(&Sm[row * 128 + seg * 8]) = v;
    } else {
      int e2 = i - 2048;
      int which = e2 >> 4, seg = e2 & 15;
      int l = which ? (l0 + 128) : (l0 - 1);
      short8 v = {0, 0, 0, 0, 0, 0, 0, 0};
      if (l >= 0 && l < 8192)
        v = *(const short8*)(xT + ((size_t)b * 8192 + l) * 128 + seg * 8);
      *(short8*)(&xedge[which * 128 + seg * 8]) = v;
    }
  }
  __syncthreads();

  // pass 1: finalize h = irfft(D) + pw + dw + bias + x (f32, in acc)
  const float* bb = bias + b * 128;
#pragma unroll
  for (int fc = 0; fc < 4; ++fc) {
    int o = wc * 64 + fc * 16 + rowk;
    float w0 = dww[o * 3], w1v = dww[o * 3 + 1], w2v = dww[o * 3 + 2];
    float bo = bb[o];
#pragma unroll
    for (int fr = 0; fr < 4; ++fr) {
#pragma unroll
      for (int j = 0; j < 4; ++j) {
        int ll = wr * 64 + fr * 16 + kg * 4 + j;
        float xm = (ll == 0)   ? bf2f(xedge[o])       : bf2f(Sm[(ll - 1) * 128 + o]);
        float x0 = bf2f(Sm[ll * 128 + o]);
        float xp = (ll == 127) ? bf2f(xedge[128 + o]) : bf2f(Sm[(ll + 1) * 128 + o]);
        acc[fr][fc][j] += w0 * xm + w1v * x0 + w2v * xp + bo + x0;
      }
    }
  }
  // pass 2: RMS row sums
#pragma unroll
  for (int fr = 0; fr < 4; ++fr) {
#pragma unroll
    for (int j = 0; j < 4; ++j) {
      float s = 0.f;
#pragma unroll
      for (int fc = 0; fc < 4; ++fc) { float v = acc[fr][fc][j]; s += v * v; }
      s += __shfl_xor(s, 1);
      s += __shfl_xor(s, 2);
      s += __shfl_xor(s, 4);
      s += __shfl_xor(s, 8);
      if (rowk == 0) rsS[wc][wr * 64 + fr * 16 + kg * 4 + j] = s;
    }
  }
  __syncthreads();
  // pass 3a: normalize * norm_w -> LDS bounce (bf16 [128][128])
#pragma unroll
  for (int fr = 0; fr < 4; ++fr) {
#pragma unroll
    for (int j = 0; j < 4; ++j) {
      int ll = wr * 64 + fr * 16 + kg * 4 + j;
      float rms = rsqrtf((rsS[0][ll] + rsS[1][ll]) * (1.0f / 128.0f) + 1e-6f);
#pragma unroll
      for (int fc = 0; fc < 4; ++fc) {
        int o = wc * 64 + fc * 16 + rowk;
        Sm[ll * 128 + o] = f2bf(acc[fr][fc][j] * rms * nw[o]);
      }
    }
  }
  __syncthreads();
  // pass 3b: coalesced short8 store of the 128x128 tile
  {
    size_t rb = (size_t)b * 8192 + l0;
#pragma unroll
    for (int it = 0; it < 8; ++it) {
      int idx = it * 256 + t;
      int row = idx >> 4, seg = idx & 15;
      *(short8*)(hn + (rb + row) * 128 + seg * 8) = *(const short8*)(&Sm[row * 128 + seg * 8]);
    }
  }
}

// ---------------- SwiGLU + residual -> out (B,C,L) f32 (input hn prenormalized) -------
__global__ __launch_bounds__(512, 2) void k_swi(const short* __restrict__ hn,
                                                const short* __restrict__ w12f,
                                                const short* __restrict__ w3f,
                                                const float* __restrict__ x,
                                                float* __restrict__ out) {
  __shared__ short smem[32768];   // 64KB: hA [64][128] | uA [64][384]; reused as tr f32[128][65]
  short* hA = smem;
  short* uA = smem + 8192;
  float* tr = (float*)smem;

  int t = threadIdx.x;
  int lane = t & 63, wv = t >> 6;
  int rb = blockIdx.x;
  int bb_ = rb >> 7;
  int l0 = (rb & 127) << 6;
  size_t row0 = (size_t)rb * 64;

  // stage hn (64x128) -> hA with col-group swizzle: hA[row][g*8+e] = hn[row][(g^(row&7))*8+e]
#pragma unroll
  for (int c = 0; c < 2; ++c) {
    int sidx = (wv * 2 + c) * 512 + lane * 8;
    int row = sidx >> 7;
    int g = (sidx >> 3) & 15;
    const short* src = hn + (row0 + row) * 128 + (g ^ (row & 7)) * 8;
    GLL16(src, &hA[sidx]);
  }
  __syncthreads();

  int wr = wv >> 2, wq = wv & 3;
  int rowk = lane & 15, kg = lane >> 4;

  f32x4 acc1[2][6], acc2[2][6];
#pragma unroll
  for (int i = 0; i < 2; ++i)
#pragma unroll
    for (int j = 0; j < 6; ++j) {
      acc1[i][j] = (f32x4){0.f, 0.f, 0.f, 0.f};
      acc2[i][j] = (f32x4){0.f, 0.f, 0.f, 0.f};
    }
#pragma unroll
  for (int ks = 0; ks < 4; ++ks) {
    bf16x8 a[2];
#pragma unroll
    for (int fr = 0; fr < 2; ++fr) {
      int rr = wr * 32 + fr * 16 + rowk;
      int gg = (ks * 4 + kg) ^ (rr & 7);
      a[fr] = *(const bf16x8*)(&hA[rr * 128 + gg * 8]);
    }
#pragma unroll
    for (int fc = 0; fc < 6; ++fc) {
      int nt = wq * 6 + fc;
      bf16x8 b1 = *(const bf16x8*)(w12f + ((size_t)(nt * 4 + ks) * 64 + lane) * 8);
      bf16x8 b2 = *(const bf16x8*)(w12f + ((size_t)((nt + 24) * 4 + ks) * 64 + lane) * 8);
#pragma unroll
      for (int fr = 0; fr < 2; ++fr) {
        acc1[fr][fc] = mfma16(a[fr], b1, acc1[fr][fc]);
        acc2[fr][fc] = mfma16(a[fr], b2, acc2[fr][fc]);
      }
    }
  }
#pragma unroll
  for (int fr = 0; fr < 2; ++fr)
#pragma unroll
    for (int fc = 0; fc < 6; ++fc)
#pragma unroll
      for (int j = 0; j < 4; ++j) {
        float a1 = acc1[fr][fc][j], a2 = acc2[fr][fc][j];
        float u = a1 / (1.f + __expf(-a1)) * a2;
        int row = wr * 32 + fr * 16 + kg * 4 + j;
        int col = wq * 96 + fc * 16 + rowk;
        int cg = (col >> 3) ^ (row & 7);
        uA[row * 384 + cg * 8 + (col & 7)] = f2bf(u);
      }
  __syncthreads();

  f32x4 acc[2][2];
#pragma unroll
  for (int i = 0; i < 2; ++i)
#pragma unroll
    for (int j = 0; j < 2; ++j) acc[i][j] = (f32x4){0.f, 0.f, 0.f, 0.f};
#pragma unroll
  for (int ks = 0; ks < 12; ++ks) {
    bf16x8 a[2];
#pragma unroll
    for (int fr = 0; fr < 2; ++fr) {
      int rr = wr * 32 + fr * 16 + rowk;
      int gg = (ks * 4 + kg) ^ (rr & 7);
      a[fr] = *(const bf16x8*)(&uA[rr * 384 + gg * 8]);
    }
#pragma unroll
    for (int fc = 0; fc < 2; ++fc) {
      int nt = wq * 2 + fc;
      bf16x8 bw = *(const bf16x8*)(w3f + ((size_t)(nt * 12 + ks) * 64 + lane) * 8);
#pragma unroll
      for (int fr = 0; fr < 2; ++fr) acc[fr][fc] = mfma16(a[fr], bw, acc[fr][fc]);
    }
  }
  __syncthreads();   // done with hA/uA -> reuse as tr
#pragma unroll
  for (int fr = 0; fr < 2; ++fr)
#pragma unroll
    for (int fc = 0; fc < 2; ++fc)
#pragma unroll
      for (int j = 0; j < 4; ++j) {
        int r = wr * 32 + fr * 16 + kg * 4 + j;
        int c = wq * 32 + fc * 16 + rowk;
        tr[c * 65 + r] = acc[fr][fc][j];
      }
  __syncthreads();
  {
    int o = t >> 2, q = t & 3;
    const float* xs = x + ((size_t)(bb_ * 128 + o)) * 8192 + l0 + q * 16;
    float* os = out + ((size_t)(bb_ * 128 + o)) * 8192 + l0 + q * 16;
#pragma unroll
    for (int e4 = 0; e4 < 4; ++e4) {
      float4 xv = *(const float4*)(xs + e4 * 4);
      float4 r;
      r.x = tr[o * 65 + q * 16 + e4 * 4 + 0] + xv.x;
      r.y = tr[o * 65 + q * 16 + e4 * 4 + 1] + xv.y;
      r.z = tr[o * 65 + q * 16 + e4 * 4 + 2] + xv.z;
      r.w = tr[o * 65 + q * 16 + e4 * 4 + 3] + xv.w;
      *(float4*)(os + e4 * 4) = r;
    }
  }
}

// ---------------- launch ----------------
extern "C" void kernel_launch(void* const* d_in, const int* in_sizes, int n_in,
                              void* d_out, int out_size, void* d_ws, size_t ws_size,
                              hipStream_t stream) {
  const float* x      = (const float*)d_in[0];
  const float* t_emb  = (const float*)d_in[1];
  const float* w_real = (const float*)d_in[2];
  const float* w_imag = (const float*)d_in[3];
  const float* shifts = (const float*)d_in[4];
  const float* pw_w   = (const float*)d_in[5];
  const float* pw_b   = (const float*)d_in[6];
  const float* dw_w   = (const float*)d_in[7];
  const float* dw_b   = (const float*)d_in[8];
  const float* norm_w = (const float*)d_in[9];
  const float* w1     = (const float*)d_in[10];
  const float* w2     = (const float*)d_in[11];
  const float* w3     = (const float*)d_in[12];
  const float* tw     = (const float*)d_in[13];
  const float* tb     = (const float*)d_in[14];
  float* out = (float*)d_out;
  char* ws = (char*)d_ws;

  short* xbf  = (short*)(ws + 0);              // 16.78 MB
  short* xT   = (short*)(ws + 16777216);       // 16.78 MB
  short* tf   = (short*)(ws + 33554432);       // 16.78 MB
  short* ti   = (short*)(ws + 50331648);       // 16.78 MB
  float* Xb   = (float*)(ws + 67108864);       // 4.19 MB
  short* Db   = (short*)(ws + 71303168);       // 2.10 MB
  short* hn   = (short*)(ws + 73400320);       // 16.78 MB
  short* w12f = (short*)(ws + 90177536);       // 196 KB
  short* w3f  = (short*)(ws + 90374144);       // 98 KB
  short* pwb  = (short*)(ws + 90472448);       // 32 KB
  float* bias = (float*)(ws + 90505216);       // 4 KB

  k_prep_x<<<2048, 256, 0, stream>>>(x, xbf, xT);
  k_prep_tf<<<4096, 256, 0, stream>>>(tf);
  k_prep_ti<<<8192, 256, 0, stream>>>(ti);
  k_prep_w<<<640, 256, 0, stream>>>(w1, w2, w3, pw_w, w12f, w3f, pwb);
  k_prep_bias<<<8, 256, 0, stream>>>(t_emb, tw, tb, pw_b, dw_b, bias);
  k_zero<<<1024, 256, 0, stream>>>((float4*)Xb, 262144);
  k_fwd<<<512, 256, 0, stream>>>(xbf, tf, Xb);
  k_spec<<<256, 512, 0, stream>>>(Xb, w_real, w_imag, shifts, Db);
  k_inv<<<512, 256, 0, stream>>>(ti, Db, xT, pwb, dw_w, bias, norm_w, hn);
  k_swi<<<1024, 512, 0, stream>>>(hn, w12f, w3f, x, out);
}